// Round 5
// baseline (615.294 us; speedup 1.0000x reference)
//
#include <hip/hip_runtime.h>
#include <hip/hip_bf16.h>
#include <math.h>

#define Bn  2
#define Sn  2048
#define Dn  1024
#define Hn  16
#define HDn 64

#define HAS_MFMA16 __has_builtin(__builtin_amdgcn_mfma_f32_16x16x16bf16_1k)

typedef __attribute__((ext_vector_type(8))) short bf16x8;
typedef __attribute__((ext_vector_type(4))) short bf16x4;
typedef __attribute__((ext_vector_type(4))) float f32x4;

__device__ __forceinline__ uint2 pack4bf(float a, float b, float c, float d) {
    union { __hip_bfloat16 h[4]; uint2 u; } p;
    p.h[0] = __float2bfloat16(a); p.h[1] = __float2bfloat16(b);
    p.h[2] = __float2bfloat16(c); p.h[3] = __float2bfloat16(d);
    return p.u;
}

__device__ __forceinline__ bf16x4 pack4bfv(float a, float b, float c, float d) {
    union { __hip_bfloat16 h[4]; bf16x4 v; } p;
    p.h[0] = __float2bfloat16(a); p.h[1] = __float2bfloat16(b);
    p.h[2] = __float2bfloat16(c); p.h[3] = __float2bfloat16(d);
    return p.v;
}

// async global->LDS, 16B per lane. lbase must be wave-uniform; g is per-lane.
__device__ __forceinline__ void g2l16(const __hip_bfloat16* g, __hip_bfloat16* lbase) {
#if __has_builtin(__builtin_amdgcn_global_load_lds)
    __builtin_amdgcn_global_load_lds(
        (const __attribute__((address_space(1))) void*)g,
        (__attribute__((address_space(3))) void*)lbase, 16, 0, 0);
#else
    const int l = threadIdx.x & 63;
    *(uint4*)((char*)lbase + l * 16) = *(const uint4*)g;
#endif
}

// ---------------------------------------------------------------------------
// fp32 -> bf16 cast, 4 elems/thread.
// ---------------------------------------------------------------------------
__global__ __launch_bounds__(256) void cast_kernel(
    const float* __restrict__ in, __hip_bfloat16* __restrict__ out)
{
    const size_t i = ((size_t)blockIdx.x * 256 + threadIdx.x) * 4;
    float4 v = *(const float4*)(in + i);
    *(uint2*)(out + i) = pack4bf(v.x, v.y, v.z, v.w);
}

// ---------------------------------------------------------------------------
// mask*cdr_weight -> bf16, elementwise (layout kept [b][q][k]).
// ---------------------------------------------------------------------------
__global__ __launch_bounds__(256) void maskprep_kernel(
    const float* __restrict__ mask, const float* __restrict__ cwp,
    __hip_bfloat16* __restrict__ Mw)
{
    const int idx = blockIdx.x * 256 + threadIdx.x;
    const float cw = cwp[0];
    float4 v = ((const float4*)mask)[idx];
    ((uint2*)Mw)[idx] = pack4bf(v.x * cw, v.y * cw, v.z * cw, v.w * cw);
}

// ---------------------------------------------------------------------------
// MFMA GEMM: out = X @ W^T + bias.  X bf16 [M=4096][K=1024], W bf16 [N=1024][K].
// 128(M) x 64(N) block tile, BK=32, 256 threads = 4 waves.
// LDS XOR swizzle applied identically at stage and frag-read -> 2-way banks.
// MODE 1: Q  — swapped ops (regs=hd): bias, *0.125, RoPE, bf16 [b,h,s,hd]
// MODE 4: K  — same, no scale
// MODE 3: V  — normal ops (regs=s):  bias, bf16 transposed [b,h,hd,s]
// MODE 2: O  — swapped ops (regs=n): bias + residual, fp32 [m][n] float4
// ---------------------------------------------------------------------------
template<int MODE>
__global__ __launch_bounds__(256) void projmm(
    const __hip_bfloat16* __restrict__ X,
    const __hip_bfloat16* __restrict__ Wb,
    const float* __restrict__ bias,
    const float* __restrict__ resid,
    void* __restrict__ outp)
{
    __shared__ __hip_bfloat16 Xs[128 * 32];
    __shared__ __hip_bfloat16 Ws[64 * 32];
    const int tid  = threadIdx.x;
    const int w    = tid >> 6, lane = tid & 63;
    const int lrow = lane & 15, lhi = lane >> 4;
    const int m0   = blockIdx.y * 128, n0 = blockIdx.x * 64;
    const int rin  = lane >> 2, cbs = lane & 3;

    f32x4 acc[8];
#pragma unroll
    for (int i = 0; i < 8; i++) acc[i] = (f32x4){0.f, 0.f, 0.f, 0.f};

    for (int k0 = 0; k0 < Dn; k0 += 32) {
        const int xr0 = w * 32 + rin;        // tile-local X rows (2 calls)
        const int xr1 = xr0 + 16;
        const int wr  = w * 16 + rin;        // tile-local W rows (1 call)
        g2l16(X  + (size_t)(m0 + xr0) * Dn + k0 + ((cbs ^ ((xr0 >> 1) & 3)) << 3),
              &Xs[(w * 32) * 32]);
        g2l16(X  + (size_t)(m0 + xr1) * Dn + k0 + ((cbs ^ ((xr1 >> 1) & 3)) << 3),
              &Xs[(w * 32 + 16) * 32]);
        g2l16(Wb + (size_t)(n0 + wr) * Dn + k0 + ((cbs ^ ((wr >> 1) & 3)) << 3),
              &Ws[(w * 16) * 32]);
        __syncthreads();

        bf16x8 FX[2], FW[4];
#pragma unroll
        for (int tm = 0; tm < 2; tm++) {
            const int r = w * 32 + tm * 16 + lrow;
            FX[tm] = *(const bf16x8*)&Xs[r * 32 + ((lhi ^ ((r >> 1) & 3)) << 3)];
        }
#pragma unroll
        for (int tn = 0; tn < 4; tn++) {
            const int r = tn * 16 + lrow;
            FW[tn] = *(const bf16x8*)&Ws[r * 32 + ((lhi ^ ((r >> 1) & 3)) << 3)];
        }
        if constexpr (MODE == 3) {
#pragma unroll
            for (int tm = 0; tm < 2; tm++)
#pragma unroll
                for (int tn = 0; tn < 4; tn++)
                    acc[tm * 4 + tn] = __builtin_amdgcn_mfma_f32_16x16x32_bf16(
                        FX[tm], FW[tn], acc[tm * 4 + tn], 0, 0, 0);
        } else {
#pragma unroll
            for (int tn = 0; tn < 4; tn++)
#pragma unroll
                for (int tm = 0; tm < 2; tm++)
                    acc[tn * 2 + tm] = __builtin_amdgcn_mfma_f32_16x16x32_bf16(
                        FW[tn], FX[tm], acc[tn * 2 + tm], 0, 0, 0);
        }
        __syncthreads();
    }

    const int h = n0 >> 6;   // N-tile(64) == head dim span

    if constexpr (MODE == 1 || MODE == 4) {
        // swapped: D rows = n (hd), D col = m. RoPE pairs in adjacent regs.
        __hip_bfloat16* outb = (__hip_bfloat16*)outp;
        const float NEG_L2C = -0.41524101186092033f;  // -log2(10000)/32
#pragma unroll
        for (int tn = 0; tn < 4; tn++) {
            const int hd0 = tn * 16 + lhi * 4;
            const float4 b4 = *(const float4*)&bias[n0 + hd0];
            const float f0 = exp2f((float)((hd0 + 0) & 31) * NEG_L2C);
            const float f1 = exp2f((float)((hd0 + 1) & 31) * NEG_L2C);
            const float f2 = exp2f((float)((hd0 + 2) & 31) * NEG_L2C);
            const float f3 = exp2f((float)((hd0 + 3) & 31) * NEG_L2C);
#pragma unroll
            for (int tm = 0; tm < 2; tm++) {
                const int m = m0 + w * 32 + tm * 16 + lrow;
                const int s = m & (Sn - 1), bb = m >> 11;
                f32x4 a = acc[tn * 2 + tm];
                float v0 = a[0] + b4.x, v1 = a[1] + b4.y;
                float v2 = a[2] + b4.z, v3 = a[3] + b4.w;
                if (MODE == 1) { v0 *= 0.125f; v1 *= 0.125f; v2 *= 0.125f; v3 *= 0.125f; }
                const float sf = (float)s;
                const float c0 = __cosf(sf * f0), c1 = __cosf(sf * f1);
                const float c2 = __cosf(sf * f2), c3 = __cosf(sf * f3);
                const float s0 = __sinf(sf * f0), s1 = __sinf(sf * f1);
                const float s2 = __sinf(sf * f2), s3 = __sinf(sf * f3);
                const float r0 = v0 * c0 - v1 * s0;   // rot[2i]   = -t[2i+1]
                const float r1 = v1 * c1 + v0 * s1;   // rot[2i+1] =  t[2i]
                const float r2 = v2 * c2 - v3 * s2;
                const float r3 = v3 * c3 + v2 * s3;
                *(uint2*)(outb + ((size_t)(bb * Hn + h) * Sn + s) * HDn + hd0) =
                    pack4bf(r0, r1, r2, r3);
            }
        }
    } else if constexpr (MODE == 3) {
        // normal: D rows = m (s), D col = n (hd). Pack along s into V^T.
        __hip_bfloat16* outb = (__hip_bfloat16*)outp;
#pragma unroll
        for (int tn = 0; tn < 4; tn++) {
            const int c = tn * 16 + lrow;              // hd
            const float bc = bias[n0 + c];
#pragma unroll
            for (int tm = 0; tm < 2; tm++) {
                const int mb = m0 + w * 32 + tm * 16 + lhi * 4;  // s base
                const int s = mb & (Sn - 1), bb = mb >> 11;
                f32x4 a = acc[tm * 4 + tn];
                *(uint2*)(outb + ((size_t)(bb * Hn + h) * HDn + c) * Sn + s) =
                    pack4bf(a[0] + bc, a[1] + bc, a[2] + bc, a[3] + bc);
            }
        }
    } else {  // MODE == 2
        // swapped: D rows = n, D col = m. float4 out + residual.
        float* outf = (float*)outp;
#pragma unroll
        for (int tn = 0; tn < 4; tn++) {
            const int nb = n0 + tn * 16 + lhi * 4;
            const float4 b4 = *(const float4*)&bias[nb];
#pragma unroll
            for (int tm = 0; tm < 2; tm++) {
                const int m = m0 + w * 32 + tm * 16 + lrow;
                f32x4 a = acc[tn * 2 + tm];
                const float4 rr = *(const float4*)&resid[(size_t)m * Dn + nb];
                *(float4*)(outf + (size_t)m * Dn + nb) =
                    make_float4(a[0] + b4.x + rr.x, a[1] + b4.y + rr.y,
                                a[2] + b4.z + rr.z, a[3] + b4.w + rr.w);
            }
        }
    }
}

// ---------------------------------------------------------------------------
// Flash attention (no-max softmax; shift-invariant, scores bounded |s|<~8).
// S^T = K·Q^T (A=K rows=k, B=Q cols=q). KEY TRICK: the S^T C-layout
// (col=lane&15=q, row=lhi*4+r=k) is EXACTLY the B-operand layout of
// v_mfma_f32_16x16x16_bf16 (B[n=lane&15][k=lhi*4+j]), so exp(S) feeds the
// PV MFMA directly in registers — no LDS round-trip, no fences, no shuffles
// in the k-loop. V^T is read as 8B bf16x4 A-frags (A[m=hd][k=lhi*4+j]).
// ---------------------------------------------------------------------------
__device__ __forceinline__ void attn_step(
    int k0, int kpre,
    const bf16x8& Qf0, const bf16x8& Qf1,
    bf16x8 (&Kc)[8], bf16x8 (&Kn)[8],
    uint2 (&Mc)[4], uint2 (&Mn)[4],
    const __hip_bfloat16* __restrict__ Kb,
    const __hip_bfloat16* __restrict__ Vb,
    const __hip_bfloat16* __restrict__ Mp,
#if !HAS_MFMA16
    __hip_bfloat16 (&PtW)[16][88],
#endif
    int lrow, int lhi,
    f32x4 (&Oc)[4], float& lsum)
{
#if HAS_MFMA16
    // V A-frags for x16 PV: Vf[kt][ch], 8B each — issued early.
    bf16x4 Vf[4][4];
#pragma unroll
    for (int kt = 0; kt < 4; kt++)
#pragma unroll
        for (int ch = 0; ch < 4; ch++)
            Vf[kt][ch] = *(const bf16x4*)(Vb + (size_t)(ch * 16 + lrow) * Sn
                                          + k0 + kt * 16 + lhi * 4);
#else
    bf16x8 Vf[8];
#pragma unroll
    for (int ch = 0; ch < 4; ch++) {
        const __hip_bfloat16* vp = Vb + (size_t)(ch * 16 + lrow) * Sn + k0 + lhi * 8;
        Vf[2 * ch]     = *(const bf16x8*)vp;
        Vf[2 * ch + 1] = *(const bf16x8*)(vp + 32);
    }
#endif
    // S^T tiles from prefetched K frags.
    f32x4 st[4];
#pragma unroll
    for (int kt = 0; kt < 4; kt++) {
        f32x4 z = (f32x4){0.f, 0.f, 0.f, 0.f};
        z = __builtin_amdgcn_mfma_f32_16x16x32_bf16(Kc[2 * kt],     Qf0, z, 0, 0, 0);
        z = __builtin_amdgcn_mfma_f32_16x16x32_bf16(Kc[2 * kt + 1], Qf1, z, 0, 0, 0);
        st[kt] = z;
    }
    // Prefetch next K tile + mask (clamped kpre on last iter; values unused).
#pragma unroll
    for (int kt = 0; kt < 4; kt++) {
        const __hip_bfloat16* kp = Kb + (size_t)(kpre + kt * 16 + lrow) * HDn + lhi * 8;
        Kn[2 * kt]     = *(const bf16x8*)kp;
        Kn[2 * kt + 1] = *(const bf16x8*)(kp + 32);
        Mn[kt] = *(const uint2*)(Mp + kpre + kt * 16 + lhi * 4);
    }
#if HAS_MFMA16
    // p = exp(s + mask) -> bf16x4 B-frags, consumed directly by x16 MFMA.
    bf16x4 pk[4];
#pragma unroll
    for (int kt = 0; kt < 4; kt++) {
        union { uint2 u; __hip_bfloat16 hh[4]; } mu; mu.u = Mc[kt];
        const float p0 = __expf(st[kt][0] + __bfloat162float(mu.hh[0]));
        const float p1 = __expf(st[kt][1] + __bfloat162float(mu.hh[1]));
        const float p2 = __expf(st[kt][2] + __bfloat162float(mu.hh[2]));
        const float p3 = __expf(st[kt][3] + __bfloat162float(mu.hh[3]));
        lsum += (p0 + p1) + (p2 + p3);
        pk[kt] = pack4bfv(p0, p1, p2, p3);
    }
#pragma unroll
    for (int ch = 0; ch < 4; ch++)
#pragma unroll
        for (int kt = 0; kt < 4; kt++)
            Oc[ch] = __builtin_amdgcn_mfma_f32_16x16x16bf16_1k(
                Vf[kt][ch], pk[kt], Oc[ch], 0, 0, 0);
#else
#pragma unroll
    for (int kt = 0; kt < 4; kt++) {
        union { uint2 u; __hip_bfloat16 hh[4]; } mu; mu.u = Mc[kt];
        const float p0 = __expf(st[kt][0] + __bfloat162float(mu.hh[0]));
        const float p1 = __expf(st[kt][1] + __bfloat162float(mu.hh[1]));
        const float p2 = __expf(st[kt][2] + __bfloat162float(mu.hh[2]));
        const float p3 = __expf(st[kt][3] + __bfloat162float(mu.hh[3]));
        lsum += (p0 + p1) + (p2 + p3);
        *(uint2*)&PtW[lrow][kt * 16 + lhi * 4] = pack4bf(p0, p1, p2, p3);
    }
    __asm__ __volatile__("" ::: "memory");
    const bf16x8 Pb0 = *(const bf16x8*)&PtW[lrow][lhi * 8];
    const bf16x8 Pb1 = *(const bf16x8*)&PtW[lrow][32 + lhi * 8];
#pragma unroll
    for (int ch = 0; ch < 4; ch++) {
        Oc[ch] = __builtin_amdgcn_mfma_f32_16x16x32_bf16(Vf[2 * ch],     Pb0, Oc[ch], 0, 0, 0);
        Oc[ch] = __builtin_amdgcn_mfma_f32_16x16x32_bf16(Vf[2 * ch + 1], Pb1, Oc[ch], 0, 0, 0);
    }
#endif
}

__global__ __launch_bounds__(256) void attn_kernel(
    const __hip_bfloat16* __restrict__ Q,   // [bh][s][hd], prescaled 1/8
    const __hip_bfloat16* __restrict__ K,   // [bh][s][hd]
    const __hip_bfloat16* __restrict__ Vt,  // [bh][hd][s]
    const __hip_bfloat16* __restrict__ Mw,  // [b][q][k] bf16, prescaled cw
    __hip_bfloat16* __restrict__ A)         // [b*S+q][D] bf16
{
#if !HAS_MFMA16
    __shared__ __align__(16) __hip_bfloat16 Pt[4][16][88];
#endif
    const int tid  = threadIdx.x;
    const int w    = tid >> 6, lane = tid & 63;
    const int lrow = lane & 15, lhi = lane >> 4;
    const int bh   = blockIdx.y, b = bh >> 4, h = bh & 15;
    const int q    = blockIdx.x * 64 + w * 16 + lrow;

    const __hip_bfloat16* Qp = Q + ((size_t)bh * Sn + q) * HDn + lhi * 8;
    const bf16x8 Qf0 = *(const bf16x8*)(Qp);
    const bf16x8 Qf1 = *(const bf16x8*)(Qp + 32);
    const __hip_bfloat16* Kb = K + (size_t)bh * Sn * HDn;
    const __hip_bfloat16* Vb = Vt + (size_t)bh * HDn * Sn;
    const __hip_bfloat16* Mp = Mw + ((size_t)b * Sn + q) * Sn;

    f32x4 Oc[4];
#pragma unroll
    for (int i = 0; i < 4; i++) Oc[i] = (f32x4){0.f, 0.f, 0.f, 0.f};
    float lsum = 0.f;

    // Prime buffer 0 (k0 = 0).
    bf16x8 Ka[8], Kb2[8]; uint2 Ma[4], Mb2[4];
#pragma unroll
    for (int kt = 0; kt < 4; kt++) {
        const __hip_bfloat16* kp = Kb + (size_t)(kt * 16 + lrow) * HDn + lhi * 8;
        Ka[2 * kt]     = *(const bf16x8*)kp;
        Ka[2 * kt + 1] = *(const bf16x8*)(kp + 32);
        Ma[kt] = *(const uint2*)(Mp + kt * 16 + lhi * 4);
    }

#if HAS_MFMA16
#define PT_ARG
#else
#define PT_ARG Pt[w],
#endif
    for (int k0 = 0; k0 < Sn; k0 += 128) {
        const int kpre2 = (k0 + 128 < Sn) ? (k0 + 128) : (Sn - 64);
#if HAS_MFMA16
        attn_step(k0,      k0 + 64, Qf0, Qf1, Ka, Kb2, Ma, Mb2,
                  Kb, Vb, Mp, lrow, lhi, Oc, lsum);
        attn_step(k0 + 64, kpre2,   Qf0, Qf1, Kb2, Ka, Mb2, Ma,
                  Kb, Vb, Mp, lrow, lhi, Oc, lsum);
#else
        attn_step(k0,      k0 + 64, Qf0, Qf1, Ka, Kb2, Ma, Mb2,
                  Kb, Vb, Mp, Pt[w], lrow, lhi, Oc, lsum);
        attn_step(k0 + 64, kpre2,   Qf0, Qf1, Kb2, Ka, Mb2, Ma,
                  Kb, Vb, Mp, Pt[w], lrow, lhi, Oc, lsum);
#endif
    }

    // Row-sum reduction across the lhi groups (once for the whole kernel).
    lsum += __shfl_xor(lsum, 16, 64);
    lsum += __shfl_xor(lsum, 32, 64);
    const float inv = 1.f / lsum;

    __hip_bfloat16* ap = A + ((size_t)(b * Sn + q)) * Dn + h * HDn;
#pragma unroll
    for (int ch = 0; ch < 4; ch++) {
        *(uint2*)(ap + ch * 16 + lhi * 4) =
            pack4bf(Oc[ch][0] * inv, Oc[ch][1] * inv, Oc[ch][2] * inv, Oc[ch][3] * inv);
    }
}

// ---------------------------------------------------------------------------
// LayerNorm over D=1024 per row; in-place safe.
// ---------------------------------------------------------------------------
__global__ __launch_bounds__(256) void ln_kernel(
    const float* __restrict__ Yin, const float* __restrict__ gamma,
    const float* __restrict__ beta, float* __restrict__ out)
{
    __shared__ float red[256];
    const int m   = blockIdx.x;
    const int tid = threadIdx.x;
    const size_t base = (size_t)m * Dn + tid * 4;
    float4 y = *(const float4*)(Yin + base);

    red[tid] = y.x + y.y + y.z + y.w; __syncthreads();
    for (int off = 128; off > 0; off >>= 1) {
        if (tid < off) red[tid] += red[tid + off];
        __syncthreads();
    }
    const float mu = red[0] * (1.f / Dn);
    __syncthreads();

    const float d0 = y.x - mu, d1 = y.y - mu, d2 = y.z - mu, d3 = y.w - mu;
    red[tid] = d0*d0 + d1*d1 + d2*d2 + d3*d3; __syncthreads();
    for (int off = 128; off > 0; off >>= 1) {
        if (tid < off) red[tid] += red[tid + off];
        __syncthreads();
    }
    const float var = red[0] * (1.f / Dn);
    const float rin = rsqrtf(var + 1e-5f);

    float4 gv = *(const float4*)(gamma + tid * 4);
    float4 bv = *(const float4*)(beta  + tid * 4);
    *(float4*)(out + base) = make_float4(d0 * rin * gv.x + bv.x,
                                         d1 * rin * gv.y + bv.y,
                                         d2 * rin * gv.z + bv.z,
                                         d3 * rin * gv.w + bv.w);
}

// ---------------------------------------------------------------------------
extern "C" void kernel_launch(void* const* d_in, const int* in_sizes, int n_in,
                              void* d_out, int out_size, void* d_ws, size_t ws_size,
                              hipStream_t stream)
{
    const float* x     = (const float*)d_in[0];
    const float* mask  = (const float*)d_in[1];
    const float* Wq    = (const float*)d_in[2];
    const float* bq    = (const float*)d_in[3];
    const float* Wk    = (const float*)d_in[4];
    const float* bk    = (const float*)d_in[5];
    const float* Wv    = (const float*)d_in[6];
    const float* bv    = (const float*)d_in[7];
    const float* Wo    = (const float*)d_in[8];
    const float* bo    = (const float*)d_in[9];
    const float* gamma = (const float*)d_in[10];
    const float* beta  = (const float*)d_in[11];
    const float* cw    = (const float*)d_in[12];
    float* out = (float*)d_out;

    const size_t MB = 1024 * 1024;
    char* ws = (char*)d_ws;
    __hip_bfloat16* Xb  = (__hip_bfloat16*)(ws);            // 8 MB (reused as Ab)
    __hip_bfloat16* Qb  = (__hip_bfloat16*)(ws +  8 * MB);  // 8 MB
    __hip_bfloat16* Kb  = (__hip_bfloat16*)(ws + 16 * MB);  // 8 MB
    __hip_bfloat16* Vtb = (__hip_bfloat16*)(ws + 24 * MB);  // 8 MB
    __hip_bfloat16* Mw  = (__hip_bfloat16*)(ws + 32 * MB);  // 16 MB
    __hip_bfloat16* Wqb = (__hip_bfloat16*)(ws + 48 * MB);  // 2 MB
    __hip_bfloat16* Wkb = (__hip_bfloat16*)(ws + 50 * MB);  // 2 MB
    __hip_bfloat16* Wvb = (__hip_bfloat16*)(ws + 52 * MB);  // 2 MB
    __hip_bfloat16* Wob = (__hip_bfloat16*)(ws + 54 * MB);  // 2 MB -> 56 MB total
    __hip_bfloat16* Ab  = Xb;  // attn out overlays Xb (dead after V projection)

    cast_kernel<<<4096, 256, 0, stream>>>(x,  Xb);
    cast_kernel<<<1024, 256, 0, stream>>>(Wq, Wqb);
    cast_kernel<<<1024, 256, 0, stream>>>(Wk, Wkb);
    cast_kernel<<<1024, 256, 0, stream>>>(Wv, Wvb);
    cast_kernel<<<1024, 256, 0, stream>>>(Wo, Wob);
    maskprep_kernel<<<(Bn * Sn * Sn / 4) / 256, 256, 0, stream>>>(mask, cw, Mw);

    dim3 g(Dn / 64, (Bn * Sn) / 128);  // (16, 32)
    projmm<1><<<g, 256, 0, stream>>>(Xb, Wqb, bq, nullptr, Qb);
    projmm<4><<<g, 256, 0, stream>>>(Xb, Wkb, bk, nullptr, Kb);
    projmm<3><<<g, 256, 0, stream>>>(Xb, Wvb, bv, nullptr, Vtb);
    attn_kernel<<<dim3(Sn / 64, Bn * Hn), 256, 0, stream>>>(Qb, Kb, Vtb, Mw, Ab);
    projmm<2><<<g, 256, 0, stream>>>(Ab, Wob, bo, x, out);
    ln_kernel<<<Bn * Sn, 256, 0, stream>>>(out, gamma, beta, out);
}

// Round 6
// 304.244 us; speedup vs baseline: 2.0224x; 2.0224x over previous
//
#include <hip/hip_runtime.h>
#include <hip/hip_bf16.h>
#include <math.h>

#define Bn  2
#define Sn  2048
#define Dn  1024
#define Hn  16
#define HDn 64

typedef __attribute__((ext_vector_type(8))) short bf16x8;
typedef __attribute__((ext_vector_type(4))) short bf16x4;
typedef __attribute__((ext_vector_type(4))) float f32x4;

__device__ __forceinline__ uint2 pack4bf(float a, float b, float c, float d) {
    union { __hip_bfloat16 h[4]; uint2 u; } p;
    p.h[0] = __float2bfloat16(a); p.h[1] = __float2bfloat16(b);
    p.h[2] = __float2bfloat16(c); p.h[3] = __float2bfloat16(d);
    return p.u;
}

__device__ __forceinline__ bf16x4 pack4bfv(float a, float b, float c, float d) {
    union { __hip_bfloat16 h[4]; bf16x4 v; } p;
    p.h[0] = __float2bfloat16(a); p.h[1] = __float2bfloat16(b);
    p.h[2] = __float2bfloat16(c); p.h[3] = __float2bfloat16(d);
    return p.v;
}

// async global->LDS, 16B per lane. lbase must be wave-uniform; g is per-lane.
__device__ __forceinline__ void g2l16(const __hip_bfloat16* g, __hip_bfloat16* lbase) {
    __builtin_amdgcn_global_load_lds(
        (const __attribute__((address_space(1))) void*)g,
        (__attribute__((address_space(3))) void*)lbase, 16, 0, 0);
}

// ---------------------------------------------------------------------------
// fp32 -> bf16 cast, 4 elems/thread.
// ---------------------------------------------------------------------------
__global__ __launch_bounds__(256) void cast_kernel(
    const float* __restrict__ in, __hip_bfloat16* __restrict__ out)
{
    const size_t i = ((size_t)blockIdx.x * 256 + threadIdx.x) * 4;
    float4 v = *(const float4*)(in + i);
    *(uint2*)(out + i) = pack4bf(v.x, v.y, v.z, v.w);
}

// ---------------------------------------------------------------------------
// mask*cdr_weight -> bf16, elementwise (layout kept [b][q][k]).
// ---------------------------------------------------------------------------
__global__ __launch_bounds__(256) void maskprep_kernel(
    const float* __restrict__ mask, const float* __restrict__ cwp,
    __hip_bfloat16* __restrict__ Mw)
{
    const int idx = blockIdx.x * 256 + threadIdx.x;
    const float cw = cwp[0];
    float4 v = ((const float4*)mask)[idx];
    ((uint2*)Mw)[idx] = pack4bf(v.x * cw, v.y * cw, v.z * cw, v.w * cw);
}

// ---------------------------------------------------------------------------
// MFMA GEMM: out = X @ W^T + bias.  X bf16 [M=4096][K=1024], W bf16 [N=1024][K].
// 128(M) x 64(N) block tile, BK=32, 256 threads = 4 waves.
// LDS XOR swizzle applied identically at stage and frag-read -> 2-way banks.
// MODE 1: Q  — swapped ops (regs=hd): bias, *0.125, RoPE, bf16 [b,h,s,hd]
// MODE 4: K  — same, no scale
// MODE 3: V  — normal ops (regs=s):  bias, bf16 transposed [b,h,hd,s]
// MODE 2: O  — swapped ops (regs=n): bias + residual, fp32 [m][n] float4
// ---------------------------------------------------------------------------
template<int MODE>
__global__ __launch_bounds__(256) void projmm(
    const __hip_bfloat16* __restrict__ X,
    const __hip_bfloat16* __restrict__ Wb,
    const float* __restrict__ bias,
    const float* __restrict__ resid,
    void* __restrict__ outp)
{
    __shared__ __hip_bfloat16 Xs[128 * 32];
    __shared__ __hip_bfloat16 Ws[64 * 32];
    const int tid  = threadIdx.x;
    const int w    = tid >> 6, lane = tid & 63;
    const int lrow = lane & 15, lhi = lane >> 4;
    const int m0   = blockIdx.y * 128, n0 = blockIdx.x * 64;
    const int rin  = lane >> 2, cbs = lane & 3;

    f32x4 acc[8];
#pragma unroll
    for (int i = 0; i < 8; i++) acc[i] = (f32x4){0.f, 0.f, 0.f, 0.f};

    for (int k0 = 0; k0 < Dn; k0 += 32) {
        const int xr0 = w * 32 + rin;        // tile-local X rows (2 calls)
        const int xr1 = xr0 + 16;
        const int wr  = w * 16 + rin;        // tile-local W rows (1 call)
        g2l16(X  + (size_t)(m0 + xr0) * Dn + k0 + ((cbs ^ ((xr0 >> 1) & 3)) << 3),
              &Xs[(w * 32) * 32]);
        g2l16(X  + (size_t)(m0 + xr1) * Dn + k0 + ((cbs ^ ((xr1 >> 1) & 3)) << 3),
              &Xs[(w * 32 + 16) * 32]);
        g2l16(Wb + (size_t)(n0 + wr) * Dn + k0 + ((cbs ^ ((wr >> 1) & 3)) << 3),
              &Ws[(w * 16) * 32]);
        __syncthreads();

        bf16x8 FX[2], FW[4];
#pragma unroll
        for (int tm = 0; tm < 2; tm++) {
            const int r = w * 32 + tm * 16 + lrow;
            FX[tm] = *(const bf16x8*)&Xs[r * 32 + ((lhi ^ ((r >> 1) & 3)) << 3)];
        }
#pragma unroll
        for (int tn = 0; tn < 4; tn++) {
            const int r = tn * 16 + lrow;
            FW[tn] = *(const bf16x8*)&Ws[r * 32 + ((lhi ^ ((r >> 1) & 3)) << 3)];
        }
        if constexpr (MODE == 3) {
#pragma unroll
            for (int tm = 0; tm < 2; tm++)
#pragma unroll
                for (int tn = 0; tn < 4; tn++)
                    acc[tm * 4 + tn] = __builtin_amdgcn_mfma_f32_16x16x32_bf16(
                        FX[tm], FW[tn], acc[tm * 4 + tn], 0, 0, 0);
        } else {
#pragma unroll
            for (int tn = 0; tn < 4; tn++)
#pragma unroll
                for (int tm = 0; tm < 2; tm++)
                    acc[tn * 2 + tm] = __builtin_amdgcn_mfma_f32_16x16x32_bf16(
                        FW[tn], FX[tm], acc[tn * 2 + tm], 0, 0, 0);
        }
        __syncthreads();
    }

    const int h = n0 >> 6;   // N-tile(64) == head dim span

    if constexpr (MODE == 1 || MODE == 4) {
        // swapped: D rows = n (hd), D col = m. RoPE pairs in adjacent regs.
        __hip_bfloat16* outb = (__hip_bfloat16*)outp;
        const float NEG_L2C = -0.41524101186092033f;  // -log2(10000)/32
#pragma unroll
        for (int tn = 0; tn < 4; tn++) {
            const int hd0 = tn * 16 + lhi * 4;
            const float4 b4 = *(const float4*)&bias[n0 + hd0];
            const float f0 = exp2f((float)((hd0 + 0) & 31) * NEG_L2C);
            const float f1 = exp2f((float)((hd0 + 1) & 31) * NEG_L2C);
            const float f2 = exp2f((float)((hd0 + 2) & 31) * NEG_L2C);
            const float f3 = exp2f((float)((hd0 + 3) & 31) * NEG_L2C);
#pragma unroll
            for (int tm = 0; tm < 2; tm++) {
                const int m = m0 + w * 32 + tm * 16 + lrow;
                const int s = m & (Sn - 1), bb = m >> 11;
                f32x4 a = acc[tn * 2 + tm];
                float v0 = a[0] + b4.x, v1 = a[1] + b4.y;
                float v2 = a[2] + b4.z, v3 = a[3] + b4.w;
                if (MODE == 1) { v0 *= 0.125f; v1 *= 0.125f; v2 *= 0.125f; v3 *= 0.125f; }
                const float sf = (float)s;
                const float c0 = __cosf(sf * f0), c1 = __cosf(sf * f1);
                const float c2 = __cosf(sf * f2), c3 = __cosf(sf * f3);
                const float s0 = __sinf(sf * f0), s1 = __sinf(sf * f1);
                const float s2 = __sinf(sf * f2), s3 = __sinf(sf * f3);
                const float r0 = v0 * c0 - v1 * s0;   // rot[2i]   = -t[2i+1]
                const float r1 = v1 * c1 + v0 * s1;   // rot[2i+1] =  t[2i]
                const float r2 = v2 * c2 - v3 * s2;
                const float r3 = v3 * c3 + v2 * s3;
                *(uint2*)(outb + ((size_t)(bb * Hn + h) * Sn + s) * HDn + hd0) =
                    pack4bf(r0, r1, r2, r3);
            }
        }
    } else if constexpr (MODE == 3) {
        // normal: D rows = m (s), D col = n (hd). Pack along s into V^T.
        __hip_bfloat16* outb = (__hip_bfloat16*)outp;
#pragma unroll
        for (int tn = 0; tn < 4; tn++) {
            const int c = tn * 16 + lrow;              // hd
            const float bc = bias[n0 + c];
#pragma unroll
            for (int tm = 0; tm < 2; tm++) {
                const int mb = m0 + w * 32 + tm * 16 + lhi * 4;  // s base
                const int s = mb & (Sn - 1), bb = mb >> 11;
                f32x4 a = acc[tm * 4 + tn];
                *(uint2*)(outb + ((size_t)(bb * Hn + h) * HDn + c) * Sn + s) =
                    pack4bf(a[0] + bc, a[1] + bc, a[2] + bc, a[3] + bc);
            }
        }
    } else {  // MODE == 2
        // swapped: D rows = n, D col = m. float4 out + residual.
        float* outf = (float*)outp;
#pragma unroll
        for (int tn = 0; tn < 4; tn++) {
            const int nb = n0 + tn * 16 + lhi * 4;
            const float4 b4 = *(const float4*)&bias[nb];
#pragma unroll
            for (int tm = 0; tm < 2; tm++) {
                const int m = m0 + w * 32 + tm * 16 + lrow;
                f32x4 a = acc[tn * 2 + tm];
                const float4 rr = *(const float4*)&resid[(size_t)m * Dn + nb];
                *(float4*)(outf + (size_t)m * Dn + nb) =
                    make_float4(a[0] + b4.x + rr.x, a[1] + b4.y + rr.y,
                                a[2] + b4.z + rr.z, a[3] + b4.w + rr.w);
            }
        }
    }
}

// ---------------------------------------------------------------------------
// Flash attention v3: LDS-staged tiles (m97 structure), double-buffered.
// Per step (64 k): DMA-stage K(64x64), V^T(64x64), mask(64q x 64k) into LDS
// via global_load_lds (coalesced, async; issued at step top, drained by the
// single end-of-step barrier). S^T = K·Q^T (x32 MFMA, frags from LDS).
// exp(S+mask) stays in registers as the x16 PV B-operand (C/D layout of S^T
// == B layout of mfma_f32_16x16x16bf16_1k — verified R5). No-max softmax
// (scores bounded |s|<~8; shift-invariant). XOR swizzle blk^(row&7) applied
// on the GLOBAL source side of the DMA (dest is lane-linear) and mirrored at
// LDS read -> <=2-way banks.
// ---------------------------------------------------------------------------
struct __align__(16) TileBuf {
    __hip_bfloat16 K[64 * 64];   // [k-local][hd]
    __hip_bfloat16 V[64 * 64];   // [hd][k-local]
    __hip_bfloat16 M[64 * 64];   // [q-local][k-local]
};

__device__ __forceinline__ void stage_tiles(
    TileBuf& t,
    const __hip_bfloat16* __restrict__ Kb,   // [s][hd] base of this bh
    const __hip_bfloat16* __restrict__ Vb,   // [hd][s] base of this bh
    const __hip_bfloat16* __restrict__ Mq0,  // mask row q0 base: + row*Sn
    int k0, int w, int lane)
{
#pragma unroll
    for (int j = 0; j < 2; j++) {
        const int row = w * 16 + j * 8 + (lane >> 3);   // 0..63 across waves
        const int blk = (lane & 7) ^ (row & 7);         // swizzled 16B block
        __hip_bfloat16* base = (__hip_bfloat16*)0;      // (set per array)
        base = &((TileBuf&)t).K[(w * 16 + j * 8) * 64];
        g2l16(Kb + (size_t)(k0 + row) * HDn + blk * 8, base);
        base = &((TileBuf&)t).V[(w * 16 + j * 8) * 64];
        g2l16(Vb + (size_t)row * Sn + k0 + blk * 8, base);
        base = &((TileBuf&)t).M[(w * 16 + j * 8) * 64];
        g2l16(Mq0 + (size_t)row * Sn + k0 + blk * 8, base);
    }
}

__global__ __launch_bounds__(256) void attn_kernel(
    const __hip_bfloat16* __restrict__ Q,   // [bh][s][hd], prescaled 1/8
    const __hip_bfloat16* __restrict__ K,   // [bh][s][hd]
    const __hip_bfloat16* __restrict__ Vt,  // [bh][hd][s]
    const __hip_bfloat16* __restrict__ Mw,  // [b][q][k] bf16, prescaled cw
    __hip_bfloat16* __restrict__ A)         // [b*S+q][D] bf16
{
    __shared__ TileBuf tb[2];               // 48 KB
    const int tid  = threadIdx.x;
    const int w    = tid >> 6, lane = tid & 63;
    const int lrow = lane & 15, lhi = lane >> 4;
    const int bh   = blockIdx.y, b = bh >> 4, h = bh & 15;
    const int q0   = blockIdx.x * 64;
    const int q    = q0 + w * 16 + lrow;

    const __hip_bfloat16* Qp  = Q + ((size_t)bh * Sn + q) * HDn + lhi * 8;
    const bf16x8 Qf0 = *(const bf16x8*)(Qp);
    const bf16x8 Qf1 = *(const bf16x8*)(Qp + 32);
    const __hip_bfloat16* Kb  = K  + (size_t)bh * Sn * HDn;
    const __hip_bfloat16* Vb  = Vt + (size_t)bh * HDn * Sn;
    const __hip_bfloat16* Mq0 = Mw + ((size_t)b * Sn + q0) * Sn;

    f32x4 Oc[4];
#pragma unroll
    for (int i = 0; i < 4; i++) Oc[i] = (f32x4){0.f, 0.f, 0.f, 0.f};
    float lsum = 0.f;

    stage_tiles(tb[0], Kb, Vb, Mq0, 0, w, lane);
    __syncthreads();   // drains DMA (vmcnt) + publishes buf 0

    for (int it = 0; it < Sn / 64; it++) {
        const int k0 = it * 64;
        // issue next tile's DMA first — hidden under this step's compute
        if (it + 1 < Sn / 64)
            stage_tiles(tb[(it + 1) & 1], Kb, Vb, Mq0, k0 + 64, w, lane);
        const TileBuf& t = tb[it & 1];

        // ---- S^T tiles (rows = k-local lhi*4+r, col = q = lrow)
        f32x4 st[4];
#pragma unroll
        for (int kt = 0; kt < 4; kt++) {
            const int rl = kt * 16 + lrow;
            const bf16x8 ka = *(const bf16x8*)&t.K[rl * 64 + ((lhi       ^ (rl & 7)) * 8)];
            const bf16x8 kc = *(const bf16x8*)&t.K[rl * 64 + (((4 + lhi) ^ (rl & 7)) * 8)];
            f32x4 z = (f32x4){0.f, 0.f, 0.f, 0.f};
            z = __builtin_amdgcn_mfma_f32_16x16x32_bf16(ka, Qf0, z, 0, 0, 0);
            z = __builtin_amdgcn_mfma_f32_16x16x32_bf16(kc, Qf1, z, 0, 0, 0);
            st[kt] = z;
        }

        // ---- p = exp(s + mask) -> bf16x4 B-frags (register-direct)
        const int rq = w * 16 + lrow;
        bf16x4 pk[4];
#pragma unroll
        for (int kt = 0; kt < 4; kt++) {
            const int eo = (((2 * kt + (lhi >> 1)) ^ (rq & 7)) * 8) + (lhi & 1) * 4;
            union { uint2 u; __hip_bfloat16 hh[4]; } mu;
            mu.u = *(const uint2*)&t.M[rq * 64 + eo];
            const float p0 = __expf(st[kt][0] + __bfloat162float(mu.hh[0]));
            const float p1 = __expf(st[kt][1] + __bfloat162float(mu.hh[1]));
            const float p2 = __expf(st[kt][2] + __bfloat162float(mu.hh[2]));
            const float p3 = __expf(st[kt][3] + __bfloat162float(mu.hh[3]));
            lsum += (p0 + p1) + (p2 + p3);
            pk[kt] = pack4bfv(p0, p1, p2, p3);
        }

        // ---- O^T += V^T · P  (x16 MFMA; V A-frags b64 from LDS)
#pragma unroll
        for (int ch = 0; ch < 4; ch++) {
            const int rv = ch * 16 + lrow;
#pragma unroll
            for (int kt = 0; kt < 4; kt++) {
                const int eo = (((2 * kt + (lhi >> 1)) ^ (rv & 7)) * 8) + (lhi & 1) * 4;
                const bf16x4 vf = *(const bf16x4*)&t.V[rv * 64 + eo];
                Oc[ch] = __builtin_amdgcn_mfma_f32_16x16x16bf16_1k(
                    vf, pk[kt], Oc[ch], 0, 0, 0);
            }
        }
        __syncthreads();   // everyone done with buf[it&1]; next DMA drained
    }

    // Row-sum reduction across the lhi groups (once for the whole kernel).
    lsum += __shfl_xor(lsum, 16, 64);
    lsum += __shfl_xor(lsum, 32, 64);
    const float inv = 1.f / lsum;

    __hip_bfloat16* ap = A + ((size_t)(b * Sn + q)) * Dn + h * HDn;
#pragma unroll
    for (int ch = 0; ch < 4; ch++) {
        *(uint2*)(ap + ch * 16 + lhi * 4) =
            pack4bf(Oc[ch][0] * inv, Oc[ch][1] * inv, Oc[ch][2] * inv, Oc[ch][3] * inv);
    }
}

// ---------------------------------------------------------------------------
// LayerNorm over D=1024 per row; in-place safe.
// ---------------------------------------------------------------------------
__global__ __launch_bounds__(256) void ln_kernel(
    const float* __restrict__ Yin, const float* __restrict__ gamma,
    const float* __restrict__ beta, float* __restrict__ out)
{
    __shared__ float red[256];
    const int m   = blockIdx.x;
    const int tid = threadIdx.x;
    const size_t base = (size_t)m * Dn + tid * 4;
    float4 y = *(const float4*)(Yin + base);

    red[tid] = y.x + y.y + y.z + y.w; __syncthreads();
    for (int off = 128; off > 0; off >>= 1) {
        if (tid < off) red[tid] += red[tid + off];
        __syncthreads();
    }
    const float mu = red[0] * (1.f / Dn);
    __syncthreads();

    const float d0 = y.x - mu, d1 = y.y - mu, d2 = y.z - mu, d3 = y.w - mu;
    red[tid] = d0*d0 + d1*d1 + d2*d2 + d3*d3; __syncthreads();
    for (int off = 128; off > 0; off >>= 1) {
        if (tid < off) red[tid] += red[tid + off];
        __syncthreads();
    }
    const float var = red[0] * (1.f / Dn);
    const float rin = rsqrtf(var + 1e-5f);

    float4 gv = *(const float4*)(gamma + tid * 4);
    float4 bv = *(const float4*)(beta  + tid * 4);
    *(float4*)(out + base) = make_float4(d0 * rin * gv.x + bv.x,
                                         d1 * rin * gv.y + bv.y,
                                         d2 * rin * gv.z + bv.z,
                                         d3 * rin * gv.w + bv.w);
}

// ---------------------------------------------------------------------------
extern "C" void kernel_launch(void* const* d_in, const int* in_sizes, int n_in,
                              void* d_out, int out_size, void* d_ws, size_t ws_size,
                              hipStream_t stream)
{
    const float* x     = (const float*)d_in[0];
    const float* mask  = (const float*)d_in[1];
    const float* Wq    = (const float*)d_in[2];
    const float* bq    = (const float*)d_in[3];
    const float* Wk    = (const float*)d_in[4];
    const float* bk    = (const float*)d_in[5];
    const float* Wv    = (const float*)d_in[6];
    const float* bv    = (const float*)d_in[7];
    const float* Wo    = (const float*)d_in[8];
    const float* bo    = (const float*)d_in[9];
    const float* gamma = (const float*)d_in[10];
    const float* beta  = (const float*)d_in[11];
    const float* cw    = (const float*)d_in[12];
    float* out = (float*)d_out;

    const size_t MB = 1024 * 1024;
    char* ws = (char*)d_ws;
    __hip_bfloat16* Xb  = (__hip_bfloat16*)(ws);            // 8 MB (reused as Ab)
    __hip_bfloat16* Qb  = (__hip_bfloat16*)(ws +  8 * MB);  // 8 MB
    __hip_bfloat16* Kb  = (__hip_bfloat16*)(ws + 16 * MB);  // 8 MB
    __hip_bfloat16* Vtb = (__hip_bfloat16*)(ws + 24 * MB);  // 8 MB
    __hip_bfloat16* Mw  = (__hip_bfloat16*)(ws + 32 * MB);  // 16 MB
    __hip_bfloat16* Wqb = (__hip_bfloat16*)(ws + 48 * MB);  // 2 MB
    __hip_bfloat16* Wkb = (__hip_bfloat16*)(ws + 50 * MB);  // 2 MB
    __hip_bfloat16* Wvb = (__hip_bfloat16*)(ws + 52 * MB);  // 2 MB
    __hip_bfloat16* Wob = (__hip_bfloat16*)(ws + 54 * MB);  // 2 MB -> 56 MB total
    __hip_bfloat16* Ab  = Xb;  // attn out overlays Xb (dead after V projection)

    cast_kernel<<<4096, 256, 0, stream>>>(x,  Xb);
    cast_kernel<<<1024, 256, 0, stream>>>(Wq, Wqb);
    cast_kernel<<<1024, 256, 0, stream>>>(Wk, Wkb);
    cast_kernel<<<1024, 256, 0, stream>>>(Wv, Wvb);
    cast_kernel<<<1024, 256, 0, stream>>>(Wo, Wob);
    maskprep_kernel<<<(Bn * Sn * Sn / 4) / 256, 256, 0, stream>>>(mask, cw, Mw);

    dim3 g(Dn / 64, (Bn * Sn) / 128);  // (16, 32)
    projmm<1><<<g, 256, 0, stream>>>(Xb, Wqb, bq, nullptr, Qb);
    projmm<4><<<g, 256, 0, stream>>>(Xb, Wkb, bk, nullptr, Kb);
    projmm<3><<<g, 256, 0, stream>>>(Xb, Wvb, bv, nullptr, Vtb);
    attn_kernel<<<dim3(Sn / 64, Bn * Hn), 256, 0, stream>>>(Qb, Kb, Vtb, Mw, Ab);
    projmm<2><<<g, 256, 0, stream>>>(Ab, Wob, bo, x, out);
    ln_kernel<<<Bn * Sn, 256, 0, stream>>>(out, gamma, beta, out);
}